// Round 1
// 133.731 us; speedup vs baseline: 1.0079x; 1.0079x over previous
//
#include <hip/hip_runtime.h>

// Problem constants: [T+1, B] = [1024, 4096] fp32, time-major
#define T1     1024
#define T      1023
#define B      4096
#define Q      1024   // B/4 column-quads per row
#define CHUNK  16
#define NCHUNK 64     // chunk c covers t in [16c, min(16c+16, 1023))
#define GPC    4      // column-groups per chunk (1024 cols each) -> 256 blocks total

#define GAMMA     0.99f
#define TD_LAMBDA 0.95f

typedef __attribute__((ext_vector_type(4))) float f4;
typedef __attribute__((ext_vector_type(4))) int   i4;

// Phase 1: per (chunk, col-quad), compose the chunk's affine steps
// adv[t] = a_t + b_t*adv[t+1]  into  adv[s] = A + Bf*adv[e].  float4 across columns.
__global__ __launch_bounds__(256) void k_compose(
    const float* __restrict__ tv, const float* __restrict__ rew,
    const int* __restrict__ st, const float* __restrict__ disc,
    float* __restrict__ AggA, float* __restrict__ AggB)
{
    int c = blockIdx.x >> 2;          // chunk 0..63
    int g = blockIdx.x & 3;           // column group 0..3
    int q = (g << 8) + threadIdx.x;   // quad index 0..1023
    int s = c * CHUNK;
    int e = min(s + CHUNK, T);

    const f4* tv4   = (const f4*)tv;
    const f4* rew4  = (const f4*)rew;
    const f4* disc4 = (const f4*)disc;
    const i4* st4   = (const i4*)st;

    f4 A  = {0.f, 0.f, 0.f, 0.f};
    f4 Bf = {1.f, 1.f, 1.f, 1.f};
    f4 tvn = tv4[(size_t)e * Q + q];          // tv[t+1] for first (highest-t) step
#pragma unroll 4
    for (int t = e - 1; t >= s; --t) {
        size_t i  = (size_t)t * Q + q;
        size_t i1 = i + Q;
        f4 d1  = disc4[i1] * GAMMA;
        f4 tvt = tv4[i];
        f4 r1  = rew4[i1];
        i4 stt = st4[i];
#pragma unroll
        for (int j = 0; j < 4; ++j) {
            float delta = r1[j] + d1[j] * tvn[j] - tvt[j];
            float wd    = d1[j] * TD_LAMBDA;
            float nl    = (stt[j] == 2) ? 0.f : 1.f;
            float a  = nl * delta;
            float bb = nl * wd;
            A[j]  = fmaf(bb, A[j], a);
            Bf[j] *= bb;
        }
        tvn = tvt;
    }
    ((f4*)AggA)[c * Q + q] = A;    // layout [c][b], quad-contiguous
    ((f4*)AggB)[c * Q + q] = Bf;
}

// Phase 2 (fused scan+replay): each block redundantly composes the suffix of
// chunk aggregates (2 MiB total, L2/L3-resident; loads independent of the
// accumulation chain so they pipeline) to get its right-boundary adv, then
// replays its chunk and emits the squared TD loss.
__global__ __launch_bounds__(256) void k_replay(
    const float* __restrict__ value, const float* __restrict__ tv,
    const float* __restrict__ rew, const int* __restrict__ st,
    const float* __restrict__ disc,
    const float* __restrict__ AggA, const float* __restrict__ AggB,
    float* __restrict__ out)
{
    int c = blockIdx.x >> 2;
    int g = blockIdx.x & 3;
    int q = (g << 8) + threadIdx.x;
    int s = c * CHUNK;
    int e = min(s + CHUNK, T);

    const f4* tv4   = (const f4*)tv;
    const f4* rew4  = (const f4*)rew;
    const f4* disc4 = (const f4*)disc;
    const f4* val4  = (const f4*)value;
    const i4* st4   = (const i4*)st;
    const f4* A4    = (const f4*)AggA;
    const f4* B4    = (const f4*)AggB;
    f4* out4 = (f4*)out;

    // Suffix walk: adv at t = e(c) is sum_{cc>c} (prod_{c<j<cc} B_j) * A_cc
    f4 S = {0.f, 0.f, 0.f, 0.f};
    f4 P = {1.f, 1.f, 1.f, 1.f};
    for (int cc = c + 1; cc < NCHUNK; ++cc) {
        f4 a = A4[cc * Q + q];
        f4 b = B4[cc * Q + q];
#pragma unroll
        for (int j = 0; j < 4; ++j) {
            S[j] = fmaf(P[j], a[j], S[j]);
            P[j] *= b[j];
        }
    }
    f4 adv = S;   // adv[e(c)]  (adv[T] = 0 terminal)

    if (c == NCHUNK - 1) {
        // tensor_extend_zero: last output row is zeros (d_out poisoned, must write)
        f4 z = {0.f, 0.f, 0.f, 0.f};
        out4[(size_t)T * Q + q] = z;
    }

    f4 tvn = tv4[(size_t)e * Q + q];
#pragma unroll 4
    for (int t = e - 1; t >= s; --t) {
        size_t i  = (size_t)t * Q + q;
        size_t i1 = i + Q;
        f4 d1  = disc4[i1] * GAMMA;
        f4 tvt = tv4[i];
        f4 r1  = rew4[i1];
        i4 stt = st4[i];
        f4 vv  = val4[i];
        f4 o;
#pragma unroll
        for (int j = 0; j < 4; ++j) {
            float delta = r1[j] + d1[j] * tvn[j] - tvt[j];
            float wd    = d1[j] * TD_LAMBDA;
            float nl    = (stt[j] == 2) ? 0.f : 1.f;
            adv[j] = nl * fmaf(wd, adv[j], delta);
            float td = adv[j] + tvt[j] - vv[j];
            o[j] = td * td;
        }
        out4[i] = o;
        tvn = tvt;
    }
}

extern "C" void kernel_launch(void* const* d_in, const int* in_sizes, int n_in,
                              void* d_out, int out_size, void* d_ws, size_t ws_size,
                              hipStream_t stream) {
    // setup_inputs order: value, target_value, reward, step_type, discount
    const float* value = (const float*)d_in[0];
    const float* tv    = (const float*)d_in[1];
    const float* rew   = (const float*)d_in[2];
    const int*   st    = (const int*)d_in[3];
    const float* disc  = (const float*)d_in[4];
    float* out = (float*)d_out;

    // Workspace: 2 arrays of NCHUNK*B floats = 2 MiB total
    float* AggA = (float*)d_ws;
    float* AggB = AggA + (size_t)NCHUNK * B;

    k_compose<<<NCHUNK * GPC, 256, 0, stream>>>(tv, rew, st, disc, AggA, AggB);
    k_replay<<<NCHUNK * GPC, 256, 0, stream>>>(value, tv, rew, st, disc, AggA, AggB, out);
}